// Round 5
// baseline (850.901 us; speedup 1.0000x reference)
//
#include <hip/hip_runtime.h>
#include <hip/hip_cooperative_groups.h>

namespace cg = cooperative_groups;

// R5: one cooperative kernel (5 phases, grid.sync between) with a checked
// fallback to 5 separate kernels sharing the same phase device-functions.
// R4 failure diagnosis: LDS union 19.9KB -> 3 blocks/CU under a 64KB
// occupancy pool -> max 768 coop blocks < 800 grid -> launch error (ignored).
// Fixes: LDS <= 10.7KB (AfL staged in two 9.2KB halves; phase-4 tile bf16),
// grid 800 with __launch_bounds__(256,4) (VGPR<=128) -> 4 blocks/CU -> 1024.

typedef float  f32x4 __attribute__((ext_vector_type(4)));
typedef float  f32x2 __attribute__((ext_vector_type(2)));
typedef short  bf16x8 __attribute__((ext_vector_type(8)));

union FR  { int4 i4; bf16x8 bf; unsigned u[4]; };
union F2U { f32x2 v; unsigned u[2]; };

#define LRELU(v) fmaxf((v), 0.01f * (v))

static __device__ inline unsigned bfr(float f) {              // RNE fp32->bf16
    unsigned u = __float_as_uint(f);
    return (u + 0x7fffu + ((u >> 16) & 1u)) >> 16;
}
static __device__ inline unsigned short bfr16(float f) { return (unsigned short)bfr(f); }
static __device__ inline float ubf(unsigned lo16) { return __uint_as_float(lo16 << 16); }

#if __has_builtin(__builtin_elementwise_fma)
static __device__ inline f32x2 pk_fma(f32x2 a, f32x2 b, f32x2 c) { return __builtin_elementwise_fma(a, b, c); }
#else
static __device__ inline f32x2 pk_fma(f32x2 a, f32x2 b, f32x2 c) { return a * b + c; }
#endif
static __device__ inline f32x2 pk_lrelu(f32x2 v) {
#if __has_builtin(__builtin_elementwise_max)
    return __builtin_elementwise_max(v, v * 0.01f);
#else
    f32x2 r; r.x = LRELU(v.x); r.y = LRELU(v.y); return r;
#endif
}
static __device__ inline float aload(float* p) {
    return __hip_atomic_load(p, __ATOMIC_RELAXED, __HIP_MEMORY_SCOPE_AGENT);
}

union SM {
    struct { int4 AfL[576]; float4 cw4s[64]; float cbl[64]; float bl[16]; float red[32]; } p1; // 10688 B
    struct { float wld[512]; float a1[16], b1[16], bl[8], red[16]; } p2;                       // 2272 B
    struct { float wld[256]; float a2[8],  b2[8],  bl[8], red[16]; } p3;                       // 1184 B
    struct { unsigned short tile[64][66]; float a3[8], b3[8]; } p4;                            // 8512 B
};

// ---------------- phase 0: lc1 A-frags + stats zero (units 0..50) ----------------
static __device__ __forceinline__ void phase0(
    int bx, int tid, const float* __restrict__ lw1,
    int4* __restrict__ afg1, float* __restrict__ stats)
{
    if (bx < 50) {
        const int pos = bx;
        for (int e = tid; e < 1152; e += 256) {
            int l = e & 63, ht = e >> 6;
            int h = (ht >= 9) ? 1 : 0, t = ht - 9 * h;
            int qq = l >> 4, o = l & 15;
            unsigned uu[4];
            #pragma unroll
            for (int p = 0; p < 4; ++p) {
                int c0 = 32 * h + 8 * qq + 2 * p;
                float w0 = lw1[(o * 64 + c0) * 450 + pos * 9 + t];
                float w1 = lw1[(o * 64 + c0 + 1) * 450 + pos * 9 + t];
                uu[p] = bfr(w0) | (bfr(w1) << 16);
            }
            int4 st = { (int)uu[0], (int)uu[1], (int)uu[2], (int)uu[3] };
            afg1[pos * 1152 + e] = st;
        }
    }
    if (bx == 50 && tid < 64) stats[tid] = 0.0f;
}

// ---------------- phase 1: conv1 + lc1 MFMA (one unit = pos x 256 samples) ----------------
static __device__ __forceinline__ void phase1_unit(
    SM& sm, int u, int tid,
    const float* __restrict__ img, const float* __restrict__ cw, const float* __restrict__ cb,
    const int4* __restrict__ afg1, const float* __restrict__ lb1,
    unsigned short* __restrict__ y1b, float* __restrict__ stats)
{
    const int pos = u >> 5, chunk = u & 31;
    const int oh = pos / 5, ow = pos % 5;
    const int lane = tid & 63, wv = tid >> 6;
    const int lane15 = lane & 15, q = lane >> 4;

    __syncthreads();
    if (tid < 64) { sm.p1.cw4s[tid] = ((const float4*)cw)[tid]; sm.p1.cbl[tid] = cb[tid]; }
    if (tid < 16) sm.p1.bl[tid] = lb1[tid * 50 + pos];
    if (tid < 32) sm.p1.red[tid] = 0.0f;

    bool km[9];
    #pragma unroll
    for (int i = 0; i < 3; i++)
        #pragma unroll
        for (int j = 0; j < 3; j++) {
            int r = oh + i - 1, c2 = 2 * ow + j - 1;
            km[i * 3 + j] = (r >= 0 && r < 10 && c2 >= 0 && c2 < 9);
        }

    const int sBase = chunk * 256 + wv * 64;
    float so[4] = {0, 0, 0, 0}, sq[4] = {0, 0, 0, 0};

    #pragma unroll
    for (int pass = 0; pass < 2; ++pass) {
        float ip[2][16];
        #pragma unroll
        for (int gg = 0; gg < 2; ++gg) {
            const float* ib = img + (size_t)(sBase + (pass * 2 + gg) * 16 + lane15) * 90;
            #pragma unroll
            for (int a = 0; a < 4; ++a) {
                int r = oh - 1 + a;
                bool rok = (r >= 0 && r < 10);
                #pragma unroll
                for (int d = 0; d < 4; ++d) {
                    int c2 = 2 * ow - 1 + d;
                    ip[gg][a * 4 + d] = (rok && c2 >= 0 && c2 < 9) ? ib[r * 9 + c2] : 0.0f;
                }
            }
        }

        f32x4 acc[2];
        acc[0] = (f32x4){0.f, 0.f, 0.f, 0.f};
        acc[1] = (f32x4){0.f, 0.f, 0.f, 0.f};

        #pragma unroll
        for (int h = 0; h < 2; ++h) {
            __syncthreads();                      // all waves done reading previous AfL half
            for (int e = tid; e < 576; e += 256)
                sm.p1.AfL[e] = afg1[pos * 1152 + h * 576 + e];
            __syncthreads();

            f32x2 wx2[4], wy2[4], wz2[4], ww2[4], cb2[4];
            #pragma unroll
            for (int p = 0; p < 4; ++p) {
                float4 wa = sm.p1.cw4s[h * 32 + q * 8 + 2 * p];
                float4 wb = sm.p1.cw4s[h * 32 + q * 8 + 2 * p + 1];
                wx2[p] = (f32x2){wa.x, wb.x};
                wy2[p] = (f32x2){wa.y, wb.y};
                wz2[p] = (f32x2){wa.z, wb.z};
                ww2[p] = (f32x2){wa.w, wb.w};
                cb2[p] = (f32x2){sm.p1.cbl[h * 32 + q * 8 + 2 * p],
                                 sm.p1.cbl[h * 32 + q * 8 + 2 * p + 1]};
            }
            #pragma unroll
            for (int t = 0; t < 9; ++t) {
                if (km[t]) {
                    const int i0 = (t / 3) * 4 + (t % 3);
                    FR fa; fa.i4 = sm.p1.AfL[t * 64 + lane];
                    #pragma unroll
                    for (int gg = 0; gg < 2; ++gg) {
                        f32x2 s0 = (f32x2)ip[gg][i0];
                        f32x2 s1 = (f32x2)ip[gg][i0 + 1];
                        f32x2 s2 = (f32x2)ip[gg][i0 + 4];
                        f32x2 s3 = (f32x2)ip[gg][i0 + 5];
                        FR fb;
                        #pragma unroll
                        for (int p = 0; p < 4; ++p) {
                            f32x2 v = pk_fma(s0, wx2[p], cb2[p]);
                            v = pk_fma(s1, wy2[p], v);
                            v = pk_fma(s2, wz2[p], v);
                            v = pk_fma(s3, ww2[p], v);
                            v = pk_lrelu(v);
                            F2U uu; uu.v = v;
                            fb.u[p] = __builtin_amdgcn_perm(uu.u[1], uu.u[0], 0x07060302u);
                        }
                        acc[gg] = __builtin_amdgcn_mfma_f32_16x16x32_bf16(fa.bf, fb.bf, acc[gg], 0, 0, 0);
                    }
                }
            }
        }

        #pragma unroll
        for (int gg = 0; gg < 2; ++gg)
            #pragma unroll
            for (int r = 0; r < 4; ++r) {
                int o = q * 4 + r;
                float v = acc[gg][r] + sm.p1.bl[o];
                v = LRELU(v);
                y1b[(size_t)(o * 50 + pos) * 8192 + sBase + (pass * 2 + gg) * 16 + lane15] = bfr16(v);
                so[r] += v; sq[r] += v * v;
            }
    }

    #pragma unroll
    for (int r = 0; r < 4; ++r) {
        #pragma unroll
        for (int m = 1; m < 16; m <<= 1) {
            so[r] += __shfl_xor(so[r], m, 16);
            sq[r] += __shfl_xor(sq[r], m, 16);
        }
        if (lane15 == 0) {
            int o = q * 4 + r;
            atomicAdd(&sm.p1.red[o], so[r]);
            atomicAdd(&sm.p1.red[16 + o], sq[r]);
        }
    }
    __syncthreads();
    if (tid < 32) atomicAdd(&stats[tid], sm.p1.red[tid]);
}

// ---------------- phase 2: lc2 (VALU fp32, bf16 IO; unit < 528) ----------------
static __device__ __forceinline__ void phase2_unit(
    SM& sm, int unit, int tid,
    const unsigned short* __restrict__ y1b,
    const float* __restrict__ lw2, const float* __restrict__ lb2,
    const float* __restrict__ g1, const float* __restrict__ be1,
    unsigned short* __restrict__ y2b, float* __restrict__ stats)
{
    const int pos = unit >> 3, chunk = unit & 7;
    const int oh = pos / 6, ow = pos % 6;
    const int lane = tid & 63;

    if (tid < 128) {
        const float* src = lw2 + tid * 264 + pos * 4;
        int o = tid >> 4, c = tid & 15;
        #pragma unroll
        for (int k = 0; k < 4; k++) sm.p2.wld[c * 32 + k * 8 + o] = src[k];
    }
    if (tid < 16) {
        float m = aload(&stats[tid]) * (1.0f / 409600.0f);
        float v = aload(&stats[16 + tid]) * (1.0f / 409600.0f) - m * m;
        float a = g1[tid] * rsqrtf(v + 1e-5f);
        sm.p2.a1[tid] = a; sm.p2.b1[tid] = be1[tid] - a * m;
        if (tid < 8) sm.p2.bl[tid] = lb2[tid * 66 + pos];
        sm.p2.red[tid] = 0.0f;
    }
    __syncthreads();

    int base[4]; float kmv[4];
    #pragma unroll
    for (int i = 0; i < 2; i++)
        #pragma unroll
        for (int j = 0; j < 2; j++) {
            int r = oh + i - 1, c2 = ow + j - 1;
            bool ok = (r >= 0 && r < 10 && c2 >= 0 && c2 < 5);
            int rc = min(max(r, 0), 9), cc2 = min(max(c2, 0), 4);
            base[i * 2 + j] = rc * 5 + cc2;
            kmv[i * 2 + j] = ok ? 1.0f : 0.0f;
        }

    const int sb = chunk * 1024 + tid * 4;
    float acc[8][4];
    #pragma unroll
    for (int o = 0; o < 8; o++)
        #pragma unroll
        for (int s = 0; s < 4; s++) acc[o][s] = sm.p2.bl[o];

    #pragma unroll 1
    for (int c = 0; c < 16; c++) {
        float av = sm.p2.a1[c], bv = sm.p2.b1[c];
        float p[4][4];
        #pragma unroll
        for (int t = 0; t < 4; t++) {
            float ap = av * kmv[t], bp = bv * kmv[t];
            uint2 U = *(const uint2*)(y1b + (size_t)(c * 50 + base[t]) * 8192 + sb);
            p[t][0] = fmaf(ap, ubf(U.x & 0xffffu), bp);
            p[t][1] = fmaf(ap, __uint_as_float(U.x & 0xffff0000u), bp);
            p[t][2] = fmaf(ap, ubf(U.y & 0xffffu), bp);
            p[t][3] = fmaf(ap, __uint_as_float(U.y & 0xffff0000u), bp);
        }
        const float4* wr = (const float4*)&sm.p2.wld[c * 32];
        #pragma unroll
        for (int t = 0; t < 4; t++) {
            float4 wa = wr[t * 2], wb = wr[t * 2 + 1];
            #pragma unroll
            for (int s = 0; s < 4; s++) {
                float pv = p[t][s];
                acc[0][s] += wa.x * pv; acc[1][s] += wa.y * pv;
                acc[2][s] += wa.z * pv; acc[3][s] += wa.w * pv;
                acc[4][s] += wb.x * pv; acc[5][s] += wb.y * pv;
                acc[6][s] += wb.z * pv; acc[7][s] += wb.w * pv;
            }
        }
    }

    #pragma unroll
    for (int o = 0; o < 8; o++) {
        float v0 = LRELU(acc[o][0]), v1 = LRELU(acc[o][1]);
        float v2 = LRELU(acc[o][2]), v3 = LRELU(acc[o][3]);
        uint2 st = { bfr(v0) | (bfr(v1) << 16), bfr(v2) | (bfr(v3) << 16) };
        *(uint2*)(y2b + (size_t)(o * 66 + pos) * 8192 + sb) = st;
        float sv = v0 + v1 + v2 + v3;
        float sqv = v0 * v0 + v1 * v1 + v2 * v2 + v3 * v3;
        #pragma unroll
        for (int m = 32; m > 0; m >>= 1) {
            sv  += __shfl_xor(sv, m, 64);
            sqv += __shfl_xor(sqv, m, 64);
        }
        if (lane == 0) { atomicAdd(&sm.p2.red[o], sv); atomicAdd(&sm.p2.red[8 + o], sqv); }
    }
    __syncthreads();
    if (tid < 16) atomicAdd(&stats[32 + tid], sm.p2.red[tid]);
}

// ---------------- phase 3: lc3 (unit < 384) ----------------
static __device__ __forceinline__ void phase3_unit(
    SM& sm, int unit, int tid,
    const unsigned short* __restrict__ y2b,
    const float* __restrict__ lw3, const float* __restrict__ lb3,
    const float* __restrict__ g2, const float* __restrict__ be2,
    unsigned short* __restrict__ y3b, float* __restrict__ stats)
{
    const int pos = unit >> 3, chunk = unit & 7;
    const int oh = pos >> 2, ow = pos & 3;
    const int lane = tid & 63;

    if (tid < 64) {
        const float* src = lw3 + tid * 192 + pos * 4;
        int o = tid >> 3, c = tid & 7;
        #pragma unroll
        for (int k = 0; k < 4; k++) sm.p3.wld[c * 32 + k * 8 + o] = src[k];
    }
    if (tid < 16) {
        if (tid < 8) {
            float m = aload(&stats[32 + tid]) * (1.0f / 540672.0f);
            float v = aload(&stats[40 + tid]) * (1.0f / 540672.0f) - m * m;
            float a = g2[tid] * rsqrtf(v + 1e-5f);
            sm.p3.a2[tid] = a; sm.p3.b2[tid] = be2[tid] - a * m;
            sm.p3.bl[tid] = lb3[tid * 48 + pos];
        }
        sm.p3.red[tid] = 0.0f;
    }
    __syncthreads();

    int base[4]; float kmv[4];
    #pragma unroll
    for (int i = 0; i < 2; i++)
        #pragma unroll
        for (int j = 0; j < 2; j++) {
            int r = oh + i - 1, c2 = 2 * ow + j - 1;
            bool ok = (r >= 0 && r < 11 && c2 >= 0 && c2 < 6);
            int rc = min(max(r, 0), 10), cc2 = min(max(c2, 0), 5);
            base[i * 2 + j] = rc * 6 + cc2;
            kmv[i * 2 + j] = ok ? 1.0f : 0.0f;
        }

    const int sb = chunk * 1024 + tid * 4;
    float acc[8][4];
    #pragma unroll
    for (int o = 0; o < 8; o++)
        #pragma unroll
        for (int s = 0; s < 4; s++) acc[o][s] = sm.p3.bl[o];

    #pragma unroll 1
    for (int c = 0; c < 8; c++) {
        float av = sm.p3.a2[c], bv = sm.p3.b2[c];
        float p[4][4];
        #pragma unroll
        for (int t = 0; t < 4; t++) {
            float ap = av * kmv[t], bp = bv * kmv[t];
            uint2 U = *(const uint2*)(y2b + (size_t)(c * 66 + base[t]) * 8192 + sb);
            p[t][0] = fmaf(ap, ubf(U.x & 0xffffu), bp);
            p[t][1] = fmaf(ap, __uint_as_float(U.x & 0xffff0000u), bp);
            p[t][2] = fmaf(ap, ubf(U.y & 0xffffu), bp);
            p[t][3] = fmaf(ap, __uint_as_float(U.y & 0xffff0000u), bp);
        }
        const float4* wr = (const float4*)&sm.p3.wld[c * 32];
        #pragma unroll
        for (int t = 0; t < 4; t++) {
            float4 wa = wr[t * 2], wb = wr[t * 2 + 1];
            #pragma unroll
            for (int s = 0; s < 4; s++) {
                float pv = p[t][s];
                acc[0][s] += wa.x * pv; acc[1][s] += wa.y * pv;
                acc[2][s] += wa.z * pv; acc[3][s] += wa.w * pv;
                acc[4][s] += wb.x * pv; acc[5][s] += wb.y * pv;
                acc[6][s] += wb.z * pv; acc[7][s] += wb.w * pv;
            }
        }
    }

    #pragma unroll
    for (int o = 0; o < 8; o++) {
        float v0 = LRELU(acc[o][0]), v1 = LRELU(acc[o][1]);
        float v2 = LRELU(acc[o][2]), v3 = LRELU(acc[o][3]);
        uint2 st = { bfr(v0) | (bfr(v1) << 16), bfr(v2) | (bfr(v3) << 16) };
        *(uint2*)(y3b + (size_t)(o * 48 + pos) * 8192 + sb) = st;
        float sv = v0 + v1 + v2 + v3;
        float sqv = v0 * v0 + v1 * v1 + v2 * v2 + v3 * v3;
        #pragma unroll
        for (int m = 32; m > 0; m >>= 1) {
            sv  += __shfl_xor(sv, m, 64);
            sqv += __shfl_xor(sqv, m, 64);
        }
        if (lane == 0) { atomicAdd(&sm.p3.red[o], sv); atomicAdd(&sm.p3.red[8 + o], sqv); }
    }
    __syncthreads();
    if (tid < 16) atomicAdd(&stats[48 + tid], sm.p3.red[tid]);
}

// ---------------- phase 4: BN3 + transpose (unit < 768) ----------------
static __device__ __forceinline__ void phase4_unit(
    SM& sm, int unit, int tid,
    const unsigned short* __restrict__ y3b,
    const float* __restrict__ g3, const float* __restrict__ be3,
    float* __restrict__ stats, float* __restrict__ out)
{
    const int chunkS = unit & 31, yy = unit >> 5;
    const int ftile = yy >> 2, sub = yy & 3;
    const int fbase = ftile * 64;
    const int sbase = chunkS * 256 + sub * 64;

    if (tid < 8) {
        float m = aload(&stats[48 + tid]) * (1.0f / 393216.0f);
        float v = aload(&stats[56 + tid]) * (1.0f / 393216.0f) - m * m;
        float a = g3[tid] * rsqrtf(v + 1e-5f);
        sm.p4.a3[tid] = a; sm.p4.b3[tid] = be3[tid] - a * m;
    }
    __syncthreads();

    #pragma unroll
    for (int rep = 0; rep < 16; rep++) {
        int idx = rep * 256 + tid;
        int f = idx >> 6, s = idx & 63;
        sm.p4.tile[f][s] = y3b[(size_t)(fbase + f) * 8192 + sbase + s];
    }
    __syncthreads();
    #pragma unroll
    for (int rep = 0; rep < 16; rep++) {
        int idx = rep * 256 + tid;
        int s = idx >> 6, f = idx & 63;
        int ff = fbase + f;
        int o = ff / 48;
        float x = ubf((unsigned)sm.p4.tile[f][s]);
        out[(size_t)(sbase + s) * 384 + ff] = sm.p4.a3[o] * x + sm.p4.b3[o];
    }
}

// ---------------- fused cooperative kernel ----------------
__global__ __launch_bounds__(256, 4) void kfused(
    const float* __restrict__ img, const float* __restrict__ cw, const float* __restrict__ cb,
    const float* __restrict__ lw1, const float* __restrict__ lb1,
    const float* __restrict__ lw2, const float* __restrict__ lb2,
    const float* __restrict__ lw3, const float* __restrict__ lb3,
    const float* __restrict__ g1, const float* __restrict__ be1,
    const float* __restrict__ g2, const float* __restrict__ be2,
    const float* __restrict__ g3, const float* __restrict__ be3,
    float* __restrict__ out, float* __restrict__ stats,
    unsigned short* __restrict__ y1b, unsigned short* __restrict__ y2b,
    unsigned short* __restrict__ y3b, int4* __restrict__ afg1)
{
    __shared__ SM sm;
    cg::grid_group grid = cg::this_grid();
    const int tid = threadIdx.x, bx = blockIdx.x;

    phase0(bx, tid, lw1, afg1, stats);
    __threadfence(); grid.sync();

    for (int u = bx; u < 1600; u += 800)
        phase1_unit(sm, u, tid, img, cw, cb, afg1, lb1, y1b, stats);
    __threadfence(); grid.sync();

    if (bx < 528) phase2_unit(sm, bx, tid, y1b, lw2, lb2, g1, be1, y2b, stats);
    __threadfence(); grid.sync();

    if (bx < 384) phase3_unit(sm, bx, tid, y2b, lw3, lb3, g2, be2, y3b, stats);
    __threadfence(); grid.sync();

    if (bx < 768) phase4_unit(sm, bx, tid, y3b, g3, be3, stats, out);
}

// ---------------- fallback kernels (same phases, natural grids) ----------------
__global__ __launch_bounds__(256) void kf0(const float* __restrict__ lw1,
                                           int4* __restrict__ afg1, float* __restrict__ stats) {
    phase0(blockIdx.x, threadIdx.x, lw1, afg1, stats);
}
__global__ __launch_bounds__(256, 4) void kf1(
    const float* __restrict__ img, const float* __restrict__ cw, const float* __restrict__ cb,
    const int4* __restrict__ afg1, const float* __restrict__ lb1,
    unsigned short* __restrict__ y1b, float* __restrict__ stats) {
    __shared__ SM sm;
    phase1_unit(sm, blockIdx.x, threadIdx.x, img, cw, cb, afg1, lb1, y1b, stats);
}
__global__ __launch_bounds__(256) void kf2(
    const unsigned short* __restrict__ y1b, const float* __restrict__ lw2,
    const float* __restrict__ lb2, const float* __restrict__ g1, const float* __restrict__ be1,
    unsigned short* __restrict__ y2b, float* __restrict__ stats) {
    __shared__ SM sm;
    phase2_unit(sm, blockIdx.x, threadIdx.x, y1b, lw2, lb2, g1, be1, y2b, stats);
}
__global__ __launch_bounds__(256) void kf3(
    const unsigned short* __restrict__ y2b, const float* __restrict__ lw3,
    const float* __restrict__ lb3, const float* __restrict__ g2, const float* __restrict__ be2,
    unsigned short* __restrict__ y3b, float* __restrict__ stats) {
    __shared__ SM sm;
    phase3_unit(sm, blockIdx.x, threadIdx.x, y2b, lw3, lb3, g2, be2, y3b, stats);
}
__global__ __launch_bounds__(256) void kf4(
    const unsigned short* __restrict__ y3b, const float* __restrict__ g3,
    const float* __restrict__ be3, float* __restrict__ stats, float* __restrict__ out) {
    __shared__ SM sm;
    phase4_unit(sm, blockIdx.x, threadIdx.x, y3b, g3, be3, stats, out);
}

extern "C" void kernel_launch(void* const* d_in, const int* in_sizes, int n_in,
                              void* d_out, int out_size, void* d_ws, size_t ws_size,
                              hipStream_t stream) {
    const float* image   = (const float*)d_in[0];
    const float* conv1_w = (const float*)d_in[1];
    const float* conv1_b = (const float*)d_in[2];
    const float* lc1_w   = (const float*)d_in[3];
    const float* lc1_b   = (const float*)d_in[4];
    const float* lc2_w   = (const float*)d_in[5];
    const float* lc2_b   = (const float*)d_in[6];
    const float* lc3_w   = (const float*)d_in[7];
    const float* lc3_b   = (const float*)d_in[8];
    const float* gamma1  = (const float*)d_in[9];
    const float* beta1   = (const float*)d_in[10];
    const float* gamma2  = (const float*)d_in[11];
    const float* beta2   = (const float*)d_in[12];
    const float* gamma3  = (const float*)d_in[13];
    const float* beta3   = (const float*)d_in[14];
    float* outp = (float*)d_out;

    char* wsb = (char*)d_ws;
    float*          stats = (float*)wsb;                       // 64 f
    unsigned short* y1b   = (unsigned short*)(wsb + 1024);     // 13,107,200 B
    unsigned short* y2b   = (unsigned short*)(wsb + 13108224); // 8,650,752 B
    unsigned short* y3b   = (unsigned short*)(wsb + 21758976); // 6,291,456 B
    int4*           afg1  = (int4*)(wsb + 28050432);           // 921,600 B

    void* args[] = {
        (void*)&image, (void*)&conv1_w, (void*)&conv1_b,
        (void*)&lc1_w, (void*)&lc1_b,
        (void*)&lc2_w, (void*)&lc2_b,
        (void*)&lc3_w, (void*)&lc3_b,
        (void*)&gamma1, (void*)&beta1,
        (void*)&gamma2, (void*)&beta2,
        (void*)&gamma3, (void*)&beta3,
        (void*)&outp, (void*)&stats,
        (void*)&y1b, (void*)&y2b, (void*)&y3b, (void*)&afg1
    };
    hipError_t err = hipLaunchCooperativeKernel((void*)kfused, dim3(800), dim3(256),
                                                args, 0, stream);
    if (err != hipSuccess) {
        // deterministic fallback: same phases as separate dispatches
        kf0<<<dim3(51),   dim3(256), 0, stream>>>(lc1_w, afg1, stats);
        kf1<<<dim3(1600), dim3(256), 0, stream>>>(image, conv1_w, conv1_b,
                                                  afg1, lc1_b, y1b, stats);
        kf2<<<dim3(528),  dim3(256), 0, stream>>>(y1b, lc2_w, lc2_b,
                                                  gamma1, beta1, y2b, stats);
        kf3<<<dim3(384),  dim3(256), 0, stream>>>(y2b, lc3_w, lc3_b,
                                                  gamma2, beta2, y3b, stats);
        kf4<<<dim3(768),  dim3(256), 0, stream>>>(y3b, gamma3, beta3, stats, outp);
    }
}

// Round 6
// 190.590 us; speedup vs baseline: 4.4646x; 4.4646x over previous
//
#include <hip/hip_runtime.h>

// Discriminator fused pipeline, R6: five separate kernels (cooperative fusion
// abandoned: R5 showed JSON-kernel gap ~98us is fixed harness overhead, and
// __launch_bounds__(256,4) caused a 64-VGPR spill disaster). All kernels use
// plain __launch_bounds__(256) so the allocator never spills.
//  kB : lc1 MFMA A-frags (bf16) + zero stats.          [51 blocks]
//  k1 : conv1 (packed fp32) + lc1 MFMA -> y1b bf16 + BN1 stats. [32x50]
//  k2 : lc2 VALU fp32, BN1 folded on bf16 uint2 loads -> y2b + BN2. [528]
//  k3 : lc3 same -> y3b + BN3.                          [384]
//  k4 : BN3 + bf16 LDS transpose -> out[8192][384] f32. [768]

typedef float  f32x4 __attribute__((ext_vector_type(4)));
typedef float  f32x2 __attribute__((ext_vector_type(2)));
typedef short  bf16x8 __attribute__((ext_vector_type(8)));

union FR  { int4 i4; bf16x8 bf; unsigned u[4]; };
union F2U { f32x2 v; unsigned u[2]; };

#define LRELU(v) fmaxf((v), 0.01f * (v))

static __device__ inline unsigned bfr(float f) {              // RNE fp32->bf16
    unsigned u = __float_as_uint(f);
    return (u + 0x7fffu + ((u >> 16) & 1u)) >> 16;
}
static __device__ inline unsigned short bfr16(float f) { return (unsigned short)bfr(f); }
static __device__ inline float ubf(unsigned lo16) { return __uint_as_float(lo16 << 16); }

#if __has_builtin(__builtin_elementwise_fma)
static __device__ inline f32x2 pk_fma(f32x2 a, f32x2 b, f32x2 c) { return __builtin_elementwise_fma(a, b, c); }
#else
static __device__ inline f32x2 pk_fma(f32x2 a, f32x2 b, f32x2 c) { return a * b + c; }
#endif
static __device__ inline f32x2 pk_lrelu(f32x2 v) {
#if __has_builtin(__builtin_elementwise_max)
    return __builtin_elementwise_max(v, v * 0.01f);
#else
    f32x2 r; r.x = LRELU(v.x); r.y = LRELU(v.y); return r;
#endif
}
static __device__ inline float aload(float* p) {
    return __hip_atomic_load(p, __ATOMIC_RELAXED, __HIP_MEMORY_SCOPE_AGENT);
}

// ---------------- kB: lc1 A-fragments + stats zero ----------------
__global__ __launch_bounds__(256) void kB_frags(
    const float* __restrict__ lw1,   // [16][64][450]
    int4* __restrict__ afg1, float* __restrict__ stats)
{
    const int bx = blockIdx.x, tid = threadIdx.x;
    if (bx == 50) { if (tid < 64) stats[tid] = 0.0f; return; }

    const int pos = bx;
    __shared__ float wt[9216];           // [pair=o*64+c][t=0..8]
    for (int e = tid; e < 9216; e += 256) {
        int pair = e / 9, t = e - 9 * pair;
        wt[e] = lw1[pair * 450 + pos * 9 + t];
    }
    __syncthreads();
    for (int e = tid; e < 1152; e += 256) {
        int l = e & 63, ht = e >> 6;
        int h = (ht >= 9) ? 1 : 0, t = ht - 9 * h;
        int q = l >> 4, o = l & 15;
        unsigned uu[4];
        #pragma unroll
        for (int p = 0; p < 4; ++p) {
            int c0 = 32 * h + 8 * q + 2 * p;
            float w0 = wt[(o * 64 + c0) * 9 + t];
            float w1 = wt[(o * 64 + c0 + 1) * 9 + t];
            uu[p] = bfr(w0) | (bfr(w1) << 16);
        }
        int4 st = { (int)uu[0], (int)uu[1], (int)uu[2], (int)uu[3] };
        afg1[pos * 1152 + e] = st;
    }
}

// ---------------- k1: conv1 + lc1 (MFMA), R3-proven ----------------
__global__ __launch_bounds__(256) void k1_lc1(
    const float* __restrict__ img,   // [8192*90]
    const float* __restrict__ cw,    // conv1_w [64*4]
    const float* __restrict__ cb,    // conv1_b [64]
    const int4* __restrict__ afg,    // lc1 A-frags
    const float* __restrict__ lb,    // lc1_b [16*50]
    unsigned short* __restrict__ y1b,// bf16 [800][8192]
    float* __restrict__ stats)       // [0..31] sum16/sq16
{
    __shared__ int4   AfL[1152];     // 18432 B
    __shared__ float4 cw4s[64];
    __shared__ float  cbl[64];
    __shared__ float  bl[16];
    __shared__ float  red[32];

    const int pos = blockIdx.y;           // 0..49
    const int oh = pos / 5, ow = pos % 5;
    const int tid = threadIdx.x;
    const int wv = tid >> 6, lane = tid & 63;
    const int lane15 = lane & 15, q = lane >> 4;

    for (int e = tid; e < 1152; e += 256) AfL[e] = afg[pos * 1152 + e];
    if (tid < 64) { cw4s[tid] = ((const float4*)cw)[tid]; cbl[tid] = cb[tid]; }
    if (tid < 16) bl[tid] = lb[tid * 50 + pos];
    if (tid < 32) red[tid] = 0.0f;
    __syncthreads();

    bool km[9];
    #pragma unroll
    for (int i = 0; i < 3; i++)
        #pragma unroll
        for (int j = 0; j < 3; j++) {
            int r = oh + i - 1, c2 = 2 * ow + j - 1;
            km[i * 3 + j] = (r >= 0 && r < 10 && c2 >= 0 && c2 < 9);
        }

    const int sBase = blockIdx.x * 256 + wv * 64;
    float ip[4][16];
    #pragma unroll
    for (int g = 0; g < 4; ++g) {
        const float* ib = img + (size_t)(sBase + g * 16 + lane15) * 90;
        #pragma unroll
        for (int a = 0; a < 4; ++a) {
            int r = oh - 1 + a;
            bool rok = (r >= 0 && r < 10);
            #pragma unroll
            for (int d = 0; d < 4; ++d) {
                int c2 = 2 * ow - 1 + d;
                ip[g][a * 4 + d] = (rok && c2 >= 0 && c2 < 9) ? ib[r * 9 + c2] : 0.0f;
            }
        }
    }

    f32x4 acc[4];
    #pragma unroll
    for (int g = 0; g < 4; ++g) acc[g] = (f32x4){0.f, 0.f, 0.f, 0.f};

    #pragma unroll
    for (int h = 0; h < 2; ++h) {
        f32x2 wx2[4], wy2[4], wz2[4], ww2[4], cb2[4];
        #pragma unroll
        for (int p = 0; p < 4; ++p) {
            float4 wa = cw4s[h * 32 + q * 8 + 2 * p];
            float4 wb = cw4s[h * 32 + q * 8 + 2 * p + 1];
            wx2[p] = (f32x2){wa.x, wb.x};
            wy2[p] = (f32x2){wa.y, wb.y};
            wz2[p] = (f32x2){wa.z, wb.z};
            ww2[p] = (f32x2){wa.w, wb.w};
            cb2[p] = (f32x2){cbl[h * 32 + q * 8 + 2 * p], cbl[h * 32 + q * 8 + 2 * p + 1]};
        }
        #pragma unroll
        for (int t = 0; t < 9; ++t) {
            const int ti = t / 3, tj = t % 3;
            const int i0 = ti * 4 + tj;
            if (km[t]) {
                FR fa; fa.i4 = AfL[(h * 9 + t) * 64 + lane];
                #pragma unroll
                for (int g = 0; g < 4; ++g) {
                    f32x2 s0 = (f32x2)ip[g][i0];
                    f32x2 s1 = (f32x2)ip[g][i0 + 1];
                    f32x2 s2 = (f32x2)ip[g][i0 + 4];
                    f32x2 s3 = (f32x2)ip[g][i0 + 5];
                    FR fb;
                    #pragma unroll
                    for (int p = 0; p < 4; ++p) {
                        f32x2 v = pk_fma(s0, wx2[p], cb2[p]);
                        v = pk_fma(s1, wy2[p], v);
                        v = pk_fma(s2, wz2[p], v);
                        v = pk_fma(s3, ww2[p], v);
                        v = pk_lrelu(v);
                        F2U uu; uu.v = v;
                        fb.u[p] = __builtin_amdgcn_perm(uu.u[1], uu.u[0], 0x07060302u);
                    }
                    acc[g] = __builtin_amdgcn_mfma_f32_16x16x32_bf16(fa.bf, fb.bf, acc[g], 0, 0, 0);
                }
            }
        }
    }

    float so[4] = {0, 0, 0, 0}, sq[4] = {0, 0, 0, 0};
    #pragma unroll
    for (int g = 0; g < 4; ++g)
        #pragma unroll
        for (int r = 0; r < 4; ++r) {
            int o = q * 4 + r;
            float v = acc[g][r] + bl[o];
            v = LRELU(v);
            y1b[(size_t)(o * 50 + pos) * 8192 + sBase + g * 16 + lane15] = bfr16(v);
            so[r] += v; sq[r] += v * v;
        }
    #pragma unroll
    for (int r = 0; r < 4; ++r) {
        #pragma unroll
        for (int m = 1; m < 16; m <<= 1) {
            so[r] += __shfl_xor(so[r], m, 16);
            sq[r] += __shfl_xor(sq[r], m, 16);
        }
        if (lane15 == 0) {
            int o = q * 4 + r;
            atomicAdd(&red[o], so[r]);
            atomicAdd(&red[16 + o], sq[r]);
        }
    }
    __syncthreads();
    if (tid < 32) atomicAdd(&stats[tid], red[tid]);
}

// ---------------- k2: lc2 (VALU fp32, bf16 uint2 IO) ----------------
__global__ __launch_bounds__(256) void k2_lc2(
    const unsigned short* __restrict__ y1b,
    const float* __restrict__ lw2, const float* __restrict__ lb2,
    const float* __restrict__ g1, const float* __restrict__ be1,
    unsigned short* __restrict__ y2b, float* __restrict__ stats)
{
    __shared__ float wld[512];
    __shared__ float a1[16], b1[16], bl[8], red[16];

    const int unit = blockIdx.x;         // 528 = 66 pos x 8 chunks
    const int pos = unit >> 3, chunk = unit & 7;
    const int oh = pos / 6, ow = pos % 6;
    const int tid = threadIdx.x, lane = tid & 63;

    if (tid < 128) {
        const float* src = lw2 + tid * 264 + pos * 4;
        int o = tid >> 4, c = tid & 15;
        #pragma unroll
        for (int k = 0; k < 4; k++) wld[c * 32 + k * 8 + o] = src[k];
    }
    if (tid < 16) {
        float m = aload(&stats[tid]) * (1.0f / 409600.0f);
        float v = aload(&stats[16 + tid]) * (1.0f / 409600.0f) - m * m;
        float a = g1[tid] * rsqrtf(v + 1e-5f);
        a1[tid] = a; b1[tid] = be1[tid] - a * m;
        if (tid < 8) bl[tid] = lb2[tid * 66 + pos];
        red[tid] = 0.0f;
    }
    __syncthreads();

    int base[4]; float kmv[4];
    #pragma unroll
    for (int i = 0; i < 2; i++)
        #pragma unroll
        for (int j = 0; j < 2; j++) {
            int r = oh + i - 1, c2 = ow + j - 1;
            bool ok = (r >= 0 && r < 10 && c2 >= 0 && c2 < 5);
            int rc = min(max(r, 0), 9), cc2 = min(max(c2, 0), 4);
            base[i * 2 + j] = rc * 5 + cc2;
            kmv[i * 2 + j] = ok ? 1.0f : 0.0f;
        }

    const int sb = chunk * 1024 + tid * 4;
    float acc[8][4];
    #pragma unroll
    for (int o = 0; o < 8; o++)
        #pragma unroll
        for (int s = 0; s < 4; s++) acc[o][s] = bl[o];

    #pragma unroll 1
    for (int c = 0; c < 16; c++) {
        float av = a1[c], bv = b1[c];
        float p[4][4];
        #pragma unroll
        for (int t = 0; t < 4; t++) {
            float ap = av * kmv[t], bp = bv * kmv[t];
            uint2 U = *(const uint2*)(y1b + (size_t)(c * 50 + base[t]) * 8192 + sb);
            p[t][0] = fmaf(ap, ubf(U.x & 0xffffu), bp);
            p[t][1] = fmaf(ap, __uint_as_float(U.x & 0xffff0000u), bp);
            p[t][2] = fmaf(ap, ubf(U.y & 0xffffu), bp);
            p[t][3] = fmaf(ap, __uint_as_float(U.y & 0xffff0000u), bp);
        }
        const float4* wr = (const float4*)&wld[c * 32];
        #pragma unroll
        for (int t = 0; t < 4; t++) {
            float4 wa = wr[t * 2], wb = wr[t * 2 + 1];
            #pragma unroll
            for (int s = 0; s < 4; s++) {
                float pv = p[t][s];
                acc[0][s] += wa.x * pv; acc[1][s] += wa.y * pv;
                acc[2][s] += wa.z * pv; acc[3][s] += wa.w * pv;
                acc[4][s] += wb.x * pv; acc[5][s] += wb.y * pv;
                acc[6][s] += wb.z * pv; acc[7][s] += wb.w * pv;
            }
        }
    }

    #pragma unroll
    for (int o = 0; o < 8; o++) {
        float v0 = LRELU(acc[o][0]), v1 = LRELU(acc[o][1]);
        float v2 = LRELU(acc[o][2]), v3 = LRELU(acc[o][3]);
        uint2 st = { bfr(v0) | (bfr(v1) << 16), bfr(v2) | (bfr(v3) << 16) };
        *(uint2*)(y2b + (size_t)(o * 66 + pos) * 8192 + sb) = st;
        float sv = v0 + v1 + v2 + v3;
        float sqv = v0 * v0 + v1 * v1 + v2 * v2 + v3 * v3;
        #pragma unroll
        for (int m = 32; m > 0; m >>= 1) {
            sv  += __shfl_xor(sv, m, 64);
            sqv += __shfl_xor(sqv, m, 64);
        }
        if (lane == 0) { atomicAdd(&red[o], sv); atomicAdd(&red[8 + o], sqv); }
    }
    __syncthreads();
    if (tid < 16) atomicAdd(&stats[32 + tid], red[tid]);
}

// ---------------- k3: lc3 ----------------
__global__ __launch_bounds__(256) void k3_lc3(
    const unsigned short* __restrict__ y2b,
    const float* __restrict__ lw3, const float* __restrict__ lb3,
    const float* __restrict__ g2, const float* __restrict__ be2,
    unsigned short* __restrict__ y3b, float* __restrict__ stats)
{
    __shared__ float wld[256];
    __shared__ float a2[8], b2[8], bl[8], red[16];

    const int unit = blockIdx.x;         // 384 = 48 pos x 8 chunks
    const int pos = unit >> 3, chunk = unit & 7;
    const int oh = pos >> 2, ow = pos & 3;
    const int tid = threadIdx.x, lane = tid & 63;

    if (tid < 64) {
        const float* src = lw3 + tid * 192 + pos * 4;
        int o = tid >> 3, c = tid & 7;
        #pragma unroll
        for (int k = 0; k < 4; k++) wld[c * 32 + k * 8 + o] = src[k];
    }
    if (tid < 16) {
        if (tid < 8) {
            float m = aload(&stats[32 + tid]) * (1.0f / 540672.0f);
            float v = aload(&stats[40 + tid]) * (1.0f / 540672.0f) - m * m;
            float a = g2[tid] * rsqrtf(v + 1e-5f);
            a2[tid] = a; b2[tid] = be2[tid] - a * m;
            bl[tid] = lb3[tid * 48 + pos];
        }
        red[tid] = 0.0f;
    }
    __syncthreads();

    int base[4]; float kmv[4];
    #pragma unroll
    for (int i = 0; i < 2; i++)
        #pragma unroll
        for (int j = 0; j < 2; j++) {
            int r = oh + i - 1, c2 = 2 * ow + j - 1;
            bool ok = (r >= 0 && r < 11 && c2 >= 0 && c2 < 6);
            int rc = min(max(r, 0), 10), cc2 = min(max(c2, 0), 5);
            base[i * 2 + j] = rc * 6 + cc2;
            kmv[i * 2 + j] = ok ? 1.0f : 0.0f;
        }

    const int sb = chunk * 1024 + tid * 4;
    float acc[8][4];
    #pragma unroll
    for (int o = 0; o < 8; o++)
        #pragma unroll
        for (int s = 0; s < 4; s++) acc[o][s] = bl[o];

    #pragma unroll 1
    for (int c = 0; c < 8; c++) {
        float av = a2[c], bv = b2[c];
        float p[4][4];
        #pragma unroll
        for (int t = 0; t < 4; t++) {
            float ap = av * kmv[t], bp = bv * kmv[t];
            uint2 U = *(const uint2*)(y2b + (size_t)(c * 66 + base[t]) * 8192 + sb);
            p[t][0] = fmaf(ap, ubf(U.x & 0xffffu), bp);
            p[t][1] = fmaf(ap, __uint_as_float(U.x & 0xffff0000u), bp);
            p[t][2] = fmaf(ap, ubf(U.y & 0xffffu), bp);
            p[t][3] = fmaf(ap, __uint_as_float(U.y & 0xffff0000u), bp);
        }
        const float4* wr = (const float4*)&wld[c * 32];
        #pragma unroll
        for (int t = 0; t < 4; t++) {
            float4 wa = wr[t * 2], wb = wr[t * 2 + 1];
            #pragma unroll
            for (int s = 0; s < 4; s++) {
                float pv = p[t][s];
                acc[0][s] += wa.x * pv; acc[1][s] += wa.y * pv;
                acc[2][s] += wa.z * pv; acc[3][s] += wa.w * pv;
                acc[4][s] += wb.x * pv; acc[5][s] += wb.y * pv;
                acc[6][s] += wb.z * pv; acc[7][s] += wb.w * pv;
            }
        }
    }

    #pragma unroll
    for (int o = 0; o < 8; o++) {
        float v0 = LRELU(acc[o][0]), v1 = LRELU(acc[o][1]);
        float v2 = LRELU(acc[o][2]), v3 = LRELU(acc[o][3]);
        uint2 st = { bfr(v0) | (bfr(v1) << 16), bfr(v2) | (bfr(v3) << 16) };
        *(uint2*)(y3b + (size_t)(o * 48 + pos) * 8192 + sb) = st;
        float sv = v0 + v1 + v2 + v3;
        float sqv = v0 * v0 + v1 * v1 + v2 * v2 + v3 * v3;
        #pragma unroll
        for (int m = 32; m > 0; m >>= 1) {
            sv  += __shfl_xor(sv, m, 64);
            sqv += __shfl_xor(sqv, m, 64);
        }
        if (lane == 0) { atomicAdd(&red[o], sv); atomicAdd(&red[8 + o], sqv); }
    }
    __syncthreads();
    if (tid < 16) atomicAdd(&stats[48 + tid], red[tid]);
}

// ---------------- k4: BN3 + transpose ----------------
__global__ __launch_bounds__(256) void k4_out(
    const unsigned short* __restrict__ y3b,
    const float* __restrict__ g3, const float* __restrict__ be3,
    float* __restrict__ stats, float* __restrict__ out)
{
    __shared__ unsigned short tile[64][66];
    __shared__ float a3[8], b3[8];
    const int unit = blockIdx.x;         // 768 = 24 (6 ftiles x 4 sub) x 32 chunks
    const int tid = threadIdx.x;
    const int chunkS = unit & 31, yy = unit >> 5;
    const int ftile = yy >> 2, sub = yy & 3;
    const int fbase = ftile * 64;
    const int sbase = chunkS * 256 + sub * 64;

    if (tid < 8) {
        float m = aload(&stats[48 + tid]) * (1.0f / 393216.0f);
        float v = aload(&stats[56 + tid]) * (1.0f / 393216.0f) - m * m;
        float a = g3[tid] * rsqrtf(v + 1e-5f);
        a3[tid] = a; b3[tid] = be3[tid] - a * m;
    }
    __syncthreads();

    #pragma unroll
    for (int rep = 0; rep < 16; rep++) {
        int idx = rep * 256 + tid;
        int f = idx >> 6, s = idx & 63;
        tile[f][s] = y3b[(size_t)(fbase + f) * 8192 + sbase + s];
    }
    __syncthreads();
    #pragma unroll
    for (int rep = 0; rep < 16; rep++) {
        int idx = rep * 256 + tid;
        int s = idx >> 6, f = idx & 63;
        int ff = fbase + f;
        int o = ff / 48;
        float x = ubf((unsigned)tile[f][s]);
        out[(size_t)(sbase + s) * 384 + ff] = a3[o] * x + b3[o];
    }
}

extern "C" void kernel_launch(void* const* d_in, const int* in_sizes, int n_in,
                              void* d_out, int out_size, void* d_ws, size_t ws_size,
                              hipStream_t stream) {
    const float* image   = (const float*)d_in[0];
    const float* conv1_w = (const float*)d_in[1];
    const float* conv1_b = (const float*)d_in[2];
    const float* lc1_w   = (const float*)d_in[3];
    const float* lc1_b   = (const float*)d_in[4];
    const float* lc2_w   = (const float*)d_in[5];
    const float* lc2_b   = (const float*)d_in[6];
    const float* lc3_w   = (const float*)d_in[7];
    const float* lc3_b   = (const float*)d_in[8];
    const float* gamma1  = (const float*)d_in[9];
    const float* beta1   = (const float*)d_in[10];
    const float* gamma2  = (const float*)d_in[11];
    const float* beta2   = (const float*)d_in[12];
    const float* gamma3  = (const float*)d_in[13];
    const float* beta3   = (const float*)d_in[14];
    float* outp = (float*)d_out;

    char* wsb = (char*)d_ws;
    float*          stats = (float*)wsb;                       // 64 f
    unsigned short* y1b   = (unsigned short*)(wsb + 1024);     // 13,107,200 B
    unsigned short* y2b   = (unsigned short*)(wsb + 13108224); // 8,650,752 B
    unsigned short* y3b   = (unsigned short*)(wsb + 21758976); // 6,291,456 B
    int4*           afg1  = (int4*)(wsb + 28050432);           // 921,600 B

    kB_frags<<<dim3(51),     dim3(256), 0, stream>>>(lc1_w, afg1, stats);
    k1_lc1  <<<dim3(32, 50), dim3(256), 0, stream>>>(image, conv1_w, conv1_b,
                                                     afg1, lc1_b, y1b, stats);
    k2_lc2  <<<dim3(528),    dim3(256), 0, stream>>>(y1b, lc2_w, lc2_b,
                                                     gamma1, beta1, y2b, stats);
    k3_lc3  <<<dim3(384),    dim3(256), 0, stream>>>(y2b, lc3_w, lc3_b,
                                                     gamma2, beta2, y3b, stats);
    k4_out  <<<dim3(768),    dim3(256), 0, stream>>>(y3b, gamma3, beta3, stats, outp);
}